// Round 11
// baseline (339.307 us; speedup 1.0000x reference)
//
#include <hip/hip_runtime.h>
#include <hip/hip_bf16.h>
#include <stdint.h>

#define BB 4
#define SQL 2048
#define SKL 2048
#define EMB 1024
#define NH 16
#define DH 64

typedef __bf16 bf16x8 __attribute__((ext_vector_type(8)));
typedef float f32x4 __attribute__((ext_vector_type(4)));

// scale folded into Q projection: 1/sqrt(64) * log2(e)
#define QSCALE 0.1803368801111144f

__device__ __forceinline__ unsigned short f2bf(float f) {
  union { float f; uint32_t u; } v; v.f = f;
  uint32_t u = v.u;
  return (unsigned short)((u + 0x7fffu + ((u >> 16) & 1u)) >> 16);
}

typedef const __attribute__((address_space(1))) void* gas_t;
typedef __attribute__((address_space(3))) void* las_t;
__device__ __forceinline__ void gld16(const void* g, void* l) {
  __builtin_amdgcn_global_load_lds((gas_t)g, (las_t)l, 16, 0, 0);
}

// ---------------- fused preprocessing: cvt(x_q) + cvt(x_kv) + wtrans x3 ----
// Blocks [0,8192): x_q cvt. [8192,16384): x_kv cvt. [16384,19456): wtrans.
__global__ void prep_kernel(const float* __restrict__ x_q, const float* __restrict__ x_kv,
                            unsigned short* __restrict__ xq_bf, unsigned short* __restrict__ xkv_bf,
                            const float* __restrict__ w0, const float* __restrict__ w1,
                            const float* __restrict__ w2,
                            unsigned short* __restrict__ o0, unsigned short* __restrict__ o1,
                            unsigned short* __restrict__ o2) {
  __shared__ float t[32][33];
  const int bid = blockIdx.x;
  if (bid < 16384) {
    const float* src = (bid < 8192) ? x_q : x_kv;
    unsigned short* dst = (bid < 8192) ? xq_bf : xkv_bf;
    int i = (bid & 8191) * 256 + threadIdx.x;
    float4 v = ((const float4*)src)[i];
    ushort4 o;
    o.x = f2bf(v.x); o.y = f2bf(v.y); o.z = f2bf(v.z); o.w = f2bf(v.w);
    ((ushort4*)dst)[i] = o;
    return;
  }
  // wtrans: w [K][N] fp32 -> w^T [N][K] bf16
  const int wb = bid - 16384;
  const int bx = wb & 31, by = (wb >> 5) & 31, bz = wb >> 10;
  const float* w = bz == 0 ? w0 : (bz == 1 ? w1 : w2);
  unsigned short* o = bz == 0 ? o0 : (bz == 1 ? o1 : o2);
  int tx = threadIdx.x & 31, ty = threadIdx.x >> 5;
  int n0 = bx * 32, k0 = by * 32;
#pragma unroll
  for (int r = 0; r < 4; r++)
    t[ty + r * 8][tx] = w[(size_t)(k0 + ty + r * 8) * EMB + n0 + tx];
  __syncthreads();
#pragma unroll
  for (int r = 0; r < 4; r++)
    o[(size_t)(n0 + ty + r * 8) * EMB + k0 + tx] = f2bf(t[tx][ty + r * 8]);
}

// ---------------- mask -> permuted halfword AND-masks (coalesced) ----------------
__global__ void maskf_kernel(const int* __restrict__ m, unsigned int* __restrict__ w) {
  unsigned int W = blockIdx.x * 256 + threadIdx.x;  // 8192*1024 words
  unsigned int row = W >> 10;
  unsigned int chunk = (W >> 5) & 31;
  unsigned int idx = W & 31;
  unsigned int q4 = idx >> 3, sub = (idx >> 1) & 3, pair = idx & 1;
  unsigned int kv = chunk * 64 + sub * 16 + q4 * 4 + pair * 2;
  int2 mm = *(const int2*)(m + (size_t)row * 2048 + kv);
  w[W] = (mm.x ? 0u : 0xffffu) | (mm.y ? 0u : 0xffff0000u);
}

// ---------------- fused projection GEMMs (z = 0:Q, 1:K, 2:V) ----------------
// v6: single-barrier double-buffer (the attn-green pattern). Old loop drained
// vmcnt(0) IMMEDIATELY after issuing staging loads (zero overlap). Now:
// prefetch kt+1 -> buf^1, compute kt from buf, ONE __syncthreads per K-step
// whose mandatory drain lands after a full compute phase covered the load
// latency. Pure __syncthreads semantics = correct by construction (full
// vmcnt+lgkm drain at barrier). BK=32, LDS 32KB -> 3 blocks/CU preserved;
// 32 barriers (same count as round-10 BK=64, isolating the overlap variable).
__global__ __launch_bounds__(256, 3) void proj_gemm_kernel(
    const unsigned short* __restrict__ Aq, const unsigned short* __restrict__ Akv,
    const unsigned short* __restrict__ W0, const unsigned short* __restrict__ W1,
    const unsigned short* __restrict__ W2,
    const float* __restrict__ bq, const float* __restrict__ bk, const float* __restrict__ bv,
    unsigned short* __restrict__ Oq, unsigned short* __restrict__ Ok,
    unsigned short* __restrict__ Ov) {
  __shared__ short As[2][4096];  // [buf][128 rows x 32 cols] bf16, 8 KB each
  __shared__ short Bs[2][4096];
  const int z = blockIdx.z;
  const unsigned short* A = (z == 0) ? Aq : Akv;
  const unsigned short* Bt = (z == 0) ? W0 : (z == 1 ? W1 : W2);
  const float* bias = (z == 0) ? bq : (z == 1 ? bk : bv);
  unsigned short* out = (z == 0) ? Oq : (z == 1 ? Ok : Ov);
  const float oscale = (z == 0) ? QSCALE : 1.0f;

  const int tid = threadIdx.x;
  const int wave = tid >> 6, lane = tid & 63;
  const int l15 = lane & 15, q4 = lane >> 4;
  const int wm = wave >> 1, wn = wave & 1;
  const int m0 = blockIdx.y * 128, n0 = blockIdx.x * 128;

  f32x4 acc[4][4];
#pragma unroll
  for (int i = 0; i < 4; i++)
#pragma unroll
    for (int j = 0; j < 4; j++) acc[i][j] = (f32x4){0.f, 0.f, 0.f, 0.f};

  const int r = tid >> 2;
  const int c = (tid & 3) * 8;
  const unsigned short* gA0 = A + (size_t)(m0 + r) * EMB + c;
  const unsigned short* gA1 = A + (size_t)(m0 + r + 64) * EMB + c;
  const unsigned short* gB0 = Bt + (size_t)(n0 + r) * EMB + c;
  const unsigned short* gB1 = Bt + (size_t)(n0 + r + 64) * EMB + c;

  // prologue: stage kt=0 into buf 0
  gld16(gA0, &As[0][tid * 8]);
  gld16(gA1, &As[0][tid * 8 + 2048]);
  gld16(gB0, &Bs[0][tid * 8]);
  gld16(gB1, &Bs[0][tid * 8 + 2048]);

  for (int kt = 0; kt < 32; kt++) {
    const int pb = kt & 1;
    // barrier drain completes buf[pb]'s staging (issued last iter / prologue)
    // AND confirms all waves finished reading buf[pb^1] (prev compute)
    __syncthreads();
    if (kt < 31) {
      const int kn = (kt + 1) * 32;
      gld16(gA0 + kn, &As[pb ^ 1][tid * 8]);
      gld16(gA1 + kn, &As[pb ^ 1][tid * 8 + 2048]);
      gld16(gB0 + kn, &Bs[pb ^ 1][tid * 8]);
      gld16(gB1 + kn, &Bs[pb ^ 1][tid * 8 + 2048]);
    }
    bf16x8 a[4], b[4];
#pragma unroll
    for (int i = 0; i < 4; i++)
      a[i] = *(const bf16x8*)(&As[pb][(wm * 64 + i * 16 + l15) * 32 + q4 * 8]);
#pragma unroll
    for (int j = 0; j < 4; j++)
      b[j] = *(const bf16x8*)(&Bs[pb][(wn * 64 + j * 16 + l15) * 32 + q4 * 8]);
#pragma unroll
    for (int i = 0; i < 4; i++)
#pragma unroll
      for (int j = 0; j < 4; j++)
        acc[i][j] = __builtin_amdgcn_mfma_f32_16x16x32_bf16(a[i], b[j], acc[i][j], 0, 0, 0);
  }

#pragma unroll
  for (int i = 0; i < 4; i++) {
    const int mrow = m0 + wm * 64 + i * 16 + q4 * 4;
#pragma unroll
    for (int j = 0; j < 4; j++) {
      const int n = n0 + wn * 64 + j * 16 + l15;
      const float bvv = bias[n];
      const int h = n >> 6, d = n & 63;
      const int bb = mrow >> 11, sq = mrow & 2047;
      if (z == 0) {
#pragma unroll
        for (int rg = 0; rg < 4; rg++)
          out[(size_t)((bb * NH + h) * SQL + sq + rg) * DH + d] =
              f2bf((acc[i][j][rg] + bvv) * oscale);
      } else if (z == 1) {
        const int chunk = sq >> 6, subK = (sq >> 4) & 3, l15k = sq & 15;
        const int halfd = d >> 5, q4k = (d >> 3) & 3, jk = d & 7;
        unsigned short* base = out + (size_t)(bb * NH + h) * (SKL * DH) + chunk * 4096 +
                               (subK * 2 + halfd) * 512 + (q4k * 16 + l15k) * 8 + jk;
#pragma unroll
        for (int rg = 0; rg < 4; rg++) base[rg * 8] = f2bf(acc[i][j][rg] + bvv);
      } else {
        const int chunk = sq >> 6, g = (sq >> 5) & 1, half = (sq >> 4) & 1, q4v = (sq >> 2) & 3;
        const int dsub = d >> 4, l15b = d & 15;
        ushort4 pk;
        pk.x = f2bf(acc[i][j][0] + bvv);
        pk.y = f2bf(acc[i][j][1] + bvv);
        pk.z = f2bf(acc[i][j][2] + bvv);
        pk.w = f2bf(acc[i][j][3] + bvv);
        *(ushort4*)(out + (size_t)(bb * NH + h) * (SKL * DH) + chunk * 4096 +
                    (g * 4 + dsub) * 512 + (q4v * 16 + l15b) * 8 + half * 4) = pk;
      }
    }
  }
}

// ---------------- fused flash attention v7: 64 Q-rows per wave (ga=4) ----------------
// round-9/10 green, byte-identical.
__global__ __launch_bounds__(256, 2) void attn_kernel(
    const unsigned short* __restrict__ Qb,  // [64][2048][64] bf16 (pre-scaled)
    const unsigned short* __restrict__ Kf,  // [64][32][4096] frag-major
    const unsigned short* __restrict__ Vf,  // [64][32][4096] frag-major
    const unsigned int* __restrict__ mw,    // [8192 rows][32 chunks][32 words]
    float* __restrict__ out) {              // [4][2048][1024]
  __shared__ short Ls[2 * 8192];  // [buf][K 4096 | V 4096]
  const int tid = threadIdx.x;
  const int wave = tid >> 6, lane = tid & 63;
  const int l15 = lane & 15, q4 = lane >> 4;
  // XCD-bijective swizzle: each XCD owns 8 whole bh's
  const int id = blockIdx.y * 8 + blockIdx.x;   // 512 blocks
  const int xcd = id & 7, idx = id >> 3;        // idx in [0,64)
  const int bh = xcd * 8 + (idx >> 3);
  const int b = bh >> 4, h = bh & 15;
  const int q0 = (idx & 7) * 256 + wave * 64;   // 64 rows per wave

  bf16x8 qa0[4], qa1[4];
#pragma unroll
  for (int ga = 0; ga < 4; ga++) {
    const unsigned short* qg = Qb + (size_t)(bh * SQL + q0 + ga * 16 + l15) * DH + q4 * 8;
    qa0[ga] = *(const bf16x8*)qg;
    qa1[ga] = *(const bf16x8*)(qg + 32);
  }

  f32x4 o[4][4], osum[4];
#pragma unroll
  for (int ga = 0; ga < 4; ga++) {
    osum[ga] = (f32x4){0.f, 0.f, 0.f, 0.f};
#pragma unroll
    for (int d = 0; d < 4; d++) o[ga][d] = (f32x4){0.f, 0.f, 0.f, 0.f};
  }
  uint4 onesu = {0x3f803f80u, 0x3f803f80u, 0x3f803f80u, 0x3f803f80u};
  const bf16x8 ones8 = __builtin_bit_cast(bf16x8, onesu);

  const unsigned short* kg = Kf + (size_t)bh * (SKL * DH);
  const unsigned short* vg = Vf + (size_t)bh * (SKL * DH);
  const unsigned int* mq[4];
#pragma unroll
  for (int ga = 0; ga < 4; ga++)
    mq[ga] = mw + (size_t)(b * SQL + q0 + ga * 16 + l15) * 1024 + q4 * 8;

  // stage chunk 0 into buf 0
  gld16(kg + tid * 8, Ls + tid * 8);
  gld16(kg + 2048 + tid * 8, Ls + 2048 + tid * 8);
  gld16(vg + tid * 8, Ls + 4096 + tid * 8);
  gld16(vg + 2048 + tid * 8, Ls + 6144 + tid * 8);
  __syncthreads();

  for (int cch = 0; cch < 32; cch++) {
    const int buf = cch & 1;
    // mask loads FIRST (so waiting on them doesn't drain the prefetch)
    uint4 mA[4], mB[4];
#pragma unroll
    for (int ga = 0; ga < 4; ga++) {
      const unsigned int* mp = mq[ga] + cch * 32;
      mA[ga] = *(const uint4*)mp;       // subs 0,1 (g=0)
      mB[ga] = *(const uint4*)(mp + 4); // subs 2,3 (g=1)
    }
    if (cch < 31) {
      const unsigned short* ks = kg + (size_t)(cch + 1) * 4096;
      const unsigned short* vs = vg + (size_t)(cch + 1) * 4096;
      short* db = Ls + (buf ^ 1) * 8192;
      gld16(ks + tid * 8, db + tid * 8);
      gld16(ks + 2048 + tid * 8, db + 2048 + tid * 8);
      gld16(vs + tid * 8, db + 4096 + tid * 8);
      gld16(vs + 2048 + tid * 8, db + 6144 + tid * 8);
    }

    const short* Kls = Ls + buf * 8192;
    const short* Vls = Kls + 4096;

#pragma unroll
    for (int g = 0; g < 2; g++) {
      uint2 pp[4][2];  // [ga][si]
#pragma unroll
      for (int si = 0; si < 2; si++) {
        const int sub = g * 2 + si;
        bf16x8 afA = *(const bf16x8*)(Kls + sub * 1024 + lane * 8);
        bf16x8 afB = *(const bf16x8*)(Kls + sub * 1024 + 512 + lane * 8);
#pragma unroll
        for (int ga = 0; ga < 4; ga++) {
          f32x4 s4 = (f32x4){0.f, 0.f, 0.f, 0.f};
          s4 = __builtin_amdgcn_mfma_f32_16x16x32_bf16(afA, qa0[ga], s4, 0, 0, 0);
          s4 = __builtin_amdgcn_mfma_f32_16x16x32_bf16(afB, qa1[ga], s4, 0, 0, 0);
          const uint4 msk = g ? mB[ga] : mA[ga];
          const unsigned int wlo = si ? msk.z : msk.x;
          const unsigned int whi = si ? msk.w : msk.y;
          union { float f; uint32_t u; } e0, e1, e2, e3;
          e0.f = __builtin_amdgcn_exp2f(s4[0]);
          e1.f = __builtin_amdgcn_exp2f(s4[1]);
          e2.f = __builtin_amdgcn_exp2f(s4[2]);
          e3.f = __builtin_amdgcn_exp2f(s4[3]);
          pp[ga][si].x = (((e0.u + 0x8000u) >> 16) | ((e1.u + 0x8000u) & 0xffff0000u)) & wlo;
          pp[ga][si].y = (((e2.u + 0x8000u) >> 16) | ((e3.u + 0x8000u) & 0xffff0000u)) & whi;
        }
      }
      bf16x8 A8[4];
#pragma unroll
      for (int ga = 0; ga < 4; ga++) {
        uint4 au = {pp[ga][0].x, pp[ga][0].y, pp[ga][1].x, pp[ga][1].y};
        A8[ga] = __builtin_bit_cast(bf16x8, au);
      }
      bf16x8 vf[4];
#pragma unroll
      for (int dsub = 0; dsub < 4; dsub++)
        vf[dsub] = *(const bf16x8*)(Vls + (g * 4 + dsub) * 512 + lane * 8);
      __builtin_amdgcn_s_setprio(1);
#pragma unroll
      for (int ga = 0; ga < 4; ga++) {
#pragma unroll
        for (int dsub = 0; dsub < 4; dsub++)
          o[ga][dsub] = __builtin_amdgcn_mfma_f32_16x16x32_bf16(A8[ga], vf[dsub], o[ga][dsub], 0, 0, 0);
        osum[ga] = __builtin_amdgcn_mfma_f32_16x16x32_bf16(A8[ga], ones8, osum[ga], 0, 0, 0);
      }
      __builtin_amdgcn_s_setprio(0);
    }
    __syncthreads();
  }

#pragma unroll
  for (int ga = 0; ga < 4; ga++)
#pragma unroll
    for (int rg = 0; rg < 4; rg++) {
      const float inv = 1.0f / osum[ga][rg];
      float* op = out + (size_t)(b * SQL + q0 + ga * 16 + q4 * 4 + rg) * 1024 + h * DH + l15;
#pragma unroll
      for (int dsub = 0; dsub < 4; dsub++) op[dsub * 16] = o[ga][dsub][rg] * inv;
    }
}

extern "C" void kernel_launch(void* const* d_in, const int* in_sizes, int n_in,
                              void* d_out, int out_size, void* d_ws, size_t ws_size,
                              hipStream_t stream) {
  const float* x_q  = (const float*)d_in[0];
  const float* x_kv = (const float*)d_in[1];
  const int*   amask = (const int*)d_in[2];
  const float* w_q  = (const float*)d_in[3];
  const float* b_q  = (const float*)d_in[4];
  const float* w_k  = (const float*)d_in[5];
  const float* b_k  = (const float*)d_in[6];
  const float* w_v  = (const float*)d_in[7];
  const float* b_v  = (const float*)d_in[8];
  float* out = (float*)d_out;

  char* ws = (char*)d_ws;
  // Phase 1 (dead after proj)
  unsigned short* xq_bf  = (unsigned short*)(ws + 0);          // 16 MB
  unsigned short* xkv_bf = (unsigned short*)(ws + 16777216);   // 16 MB
  unsigned short* wqt    = (unsigned short*)(ws + 33554432);   // 2 MB
  unsigned short* wkt    = (unsigned short*)(ws + 35651584);   // 2 MB
  unsigned short* wvt    = (unsigned short*)(ws + 37748736);   // 2 MB
  // Phase 2 (live into attn)
  unsigned short* Qb     = (unsigned short*)(ws + 39845888);   // 16 MB
  unsigned short* Kfb    = (unsigned short*)(ws + 56623104);   // 16 MB
  unsigned short* Vfb    = (unsigned short*)(ws + 73400320);   // 16 MB
  // mask written AFTER proj, overlaying dead phase-1 region
  unsigned int*   M32    = (unsigned int*)(ws + 0);            // 32 MB

  prep_kernel<<<19456, 256, 0, stream>>>(x_q, x_kv, xq_bf, xkv_bf,
                                         w_q, w_k, w_v, wqt, wkt, wvt);
  proj_gemm_kernel<<<dim3(8, 64, 3), 256, 0, stream>>>(
      xq_bf, xkv_bf, wqt, wkt, wvt, b_q, b_k, b_v, Qb, Kfb, Vfb);
  maskf_kernel<<<32768, 256, 0, stream>>>(amask, M32);
  attn_kernel<<<dim3(8, 64), 256, 0, stream>>>(Qb, Kfb, Vfb, M32, out);
}

// Round 12
// 330.562 us; speedup vs baseline: 1.0265x; 1.0265x over previous
//
#include <hip/hip_runtime.h>
#include <hip/hip_bf16.h>
#include <stdint.h>

#define BB 4
#define SQL 2048
#define SKL 2048
#define EMB 1024
#define NH 16
#define DH 64

typedef __bf16 bf16x8 __attribute__((ext_vector_type(8)));
typedef float f32x4 __attribute__((ext_vector_type(4)));

// scale folded into Q projection: 1/sqrt(64) * log2(e)
#define QSCALE 0.1803368801111144f

__device__ __forceinline__ unsigned short f2bf(float f) {
  union { float f; uint32_t u; } v; v.f = f;
  uint32_t u = v.u;
  return (unsigned short)((u + 0x7fffu + ((u >> 16) & 1u)) >> 16);
}

typedef const __attribute__((address_space(1))) void* gas_t;
typedef __attribute__((address_space(3))) void* las_t;
__device__ __forceinline__ void gld16(const void* g, void* l) {
  __builtin_amdgcn_global_load_lds((gas_t)g, (las_t)l, 16, 0, 0);
}

// ---------------- fused preprocessing: cvt(x_q) + cvt(x_kv) + wtrans x3 ----
// Blocks [0,8192): x_q cvt. [8192,16384): x_kv cvt. [16384,19456): wtrans.
__global__ void prep_kernel(const float* __restrict__ x_q, const float* __restrict__ x_kv,
                            unsigned short* __restrict__ xq_bf, unsigned short* __restrict__ xkv_bf,
                            const float* __restrict__ w0, const float* __restrict__ w1,
                            const float* __restrict__ w2,
                            unsigned short* __restrict__ o0, unsigned short* __restrict__ o1,
                            unsigned short* __restrict__ o2) {
  __shared__ float t[32][33];
  const int bid = blockIdx.x;
  if (bid < 16384) {
    const float* src = (bid < 8192) ? x_q : x_kv;
    unsigned short* dst = (bid < 8192) ? xq_bf : xkv_bf;
    int i = (bid & 8191) * 256 + threadIdx.x;
    float4 v = ((const float4*)src)[i];
    ushort4 o;
    o.x = f2bf(v.x); o.y = f2bf(v.y); o.z = f2bf(v.z); o.w = f2bf(v.w);
    ((ushort4*)dst)[i] = o;
    return;
  }
  // wtrans: w [K][N] fp32 -> w^T [N][K] bf16
  const int wb = bid - 16384;
  const int bx = wb & 31, by = (wb >> 5) & 31, bz = wb >> 10;
  const float* w = bz == 0 ? w0 : (bz == 1 ? w1 : w2);
  unsigned short* o = bz == 0 ? o0 : (bz == 1 ? o1 : o2);
  int tx = threadIdx.x & 31, ty = threadIdx.x >> 5;
  int n0 = bx * 32, k0 = by * 32;
#pragma unroll
  for (int r = 0; r < 4; r++)
    t[ty + r * 8][tx] = w[(size_t)(k0 + ty + r * 8) * EMB + n0 + tx];
  __syncthreads();
#pragma unroll
  for (int r = 0; r < 4; r++)
    o[(size_t)(n0 + ty + r * 8) * EMB + k0 + tx] = f2bf(t[tx][ty + r * 8]);
}

// ---------------- mask -> permuted halfword AND-masks (coalesced) ----------------
__global__ void maskf_kernel(const int* __restrict__ m, unsigned int* __restrict__ w) {
  unsigned int W = blockIdx.x * 256 + threadIdx.x;  // 8192*1024 words
  unsigned int row = W >> 10;
  unsigned int chunk = (W >> 5) & 31;
  unsigned int idx = W & 31;
  unsigned int q4 = idx >> 3, sub = (idx >> 1) & 3, pair = idx & 1;
  unsigned int kv = chunk * 64 + sub * 16 + q4 * 4 + pair * 2;
  int2 mm = *(const int2*)(m + (size_t)row * 2048 + kv);
  w[W] = (mm.x ? 0u : 0xffffu) | (mm.y ? 0u : 0xffff0000u);
}

// ---------------- fused projection GEMMs (z = 0:Q, 1:K, 2:V) ----------------
// round-10 green (BK=64, 2-phase): best measured proj config. Round-11's
// single-barrier dbuf regressed (+7.6 us) -- proj's ~300cy compute phase is
// too short to cover staging latency, so dbuf paid overhead for no overlap.
__global__ __launch_bounds__(256, 3) void proj_gemm_kernel(
    const unsigned short* __restrict__ Aq, const unsigned short* __restrict__ Akv,
    const unsigned short* __restrict__ W0, const unsigned short* __restrict__ W1,
    const unsigned short* __restrict__ W2,
    const float* __restrict__ bq, const float* __restrict__ bk, const float* __restrict__ bv,
    unsigned short* __restrict__ Oq, unsigned short* __restrict__ Ok,
    unsigned short* __restrict__ Ov) {
  __shared__ short As[128 * 64];  // [128 rows][64 cols] bf16, 16 KB
  __shared__ short Bs[128 * 64];
  const int z = blockIdx.z;
  const unsigned short* A = (z == 0) ? Aq : Akv;
  const unsigned short* Bt = (z == 0) ? W0 : (z == 1 ? W1 : W2);
  const float* bias = (z == 0) ? bq : (z == 1 ? bk : bv);
  unsigned short* out = (z == 0) ? Oq : (z == 1 ? Ok : Ov);
  const float oscale = (z == 0) ? QSCALE : 1.0f;

  const int tid = threadIdx.x;
  const int wave = tid >> 6, lane = tid & 63;
  const int l15 = lane & 15, q4 = lane >> 4;
  const int wm = wave >> 1, wn = wave & 1;
  const int m0 = blockIdx.y * 128, n0 = blockIdx.x * 128;

  f32x4 acc[4][4];
#pragma unroll
  for (int i = 0; i < 4; i++)
#pragma unroll
    for (int j = 0; j < 4; j++) acc[i][j] = (f32x4){0.f, 0.f, 0.f, 0.f};

  // staging map: thread tid covers (row = tid>>3, col8 = (tid&7)*8); one
  // gld16 pass = 32 rows; 4 passes = 128 rows. LDS linear offset tid*8
  // = row*64 + col8  ==> row-major [128][64], gld16 wave-uniform-safe.
  const int r = tid >> 3;
  const int c = (tid & 7) * 8;
  const unsigned short* gA = A + (size_t)(m0 + r) * EMB + c;
  const unsigned short* gB = Bt + (size_t)(n0 + r) * EMB + c;
  short* lA = As + tid * 8;
  short* lB = Bs + tid * 8;

  for (int kt = 0; kt < EMB / 64; kt++) {
    __syncthreads();
#pragma unroll
    for (int p = 0; p < 4; p++) {
      gld16(gA + (size_t)p * 32 * EMB + kt * 64, lA + p * 2048);
      gld16(gB + (size_t)p * 32 * EMB + kt * 64, lB + p * 2048);
    }
    __syncthreads();
#pragma unroll
    for (int kk = 0; kk < 2; kk++) {
      bf16x8 a[4], b[4];
#pragma unroll
      for (int i = 0; i < 4; i++)
        a[i] = *(const bf16x8*)(As + (wm * 64 + i * 16 + l15) * 64 + kk * 32 + q4 * 8);
#pragma unroll
      for (int j = 0; j < 4; j++)
        b[j] = *(const bf16x8*)(Bs + (wn * 64 + j * 16 + l15) * 64 + kk * 32 + q4 * 8);
#pragma unroll
      for (int i = 0; i < 4; i++)
#pragma unroll
        for (int j = 0; j < 4; j++)
          acc[i][j] = __builtin_amdgcn_mfma_f32_16x16x32_bf16(a[i], b[j], acc[i][j], 0, 0, 0);
    }
  }

#pragma unroll
  for (int i = 0; i < 4; i++) {
    const int mrow = m0 + wm * 64 + i * 16 + q4 * 4;
#pragma unroll
    for (int j = 0; j < 4; j++) {
      const int n = n0 + wn * 64 + j * 16 + l15;
      const float bvv = bias[n];
      const int h = n >> 6, d = n & 63;
      const int bb = mrow >> 11, sq = mrow & 2047;
      if (z == 0) {
#pragma unroll
        for (int rg = 0; rg < 4; rg++)
          out[(size_t)((bb * NH + h) * SQL + sq + rg) * DH + d] =
              f2bf((acc[i][j][rg] + bvv) * oscale);
      } else if (z == 1) {
        const int chunk = sq >> 6, subK = (sq >> 4) & 3, l15k = sq & 15;
        const int halfd = d >> 5, q4k = (d >> 3) & 3, jk = d & 7;
        unsigned short* base = out + (size_t)(bb * NH + h) * (SKL * DH) + chunk * 4096 +
                               (subK * 2 + halfd) * 512 + (q4k * 16 + l15k) * 8 + jk;
#pragma unroll
        for (int rg = 0; rg < 4; rg++) base[rg * 8] = f2bf(acc[i][j][rg] + bvv);
      } else {
        const int chunk = sq >> 6, g = (sq >> 5) & 1, half = (sq >> 4) & 1, q4v = (sq >> 2) & 3;
        const int dsub = d >> 4, l15b = d & 15;
        ushort4 pk;
        pk.x = f2bf(acc[i][j][0] + bvv);
        pk.y = f2bf(acc[i][j][1] + bvv);
        pk.z = f2bf(acc[i][j][2] + bvv);
        pk.w = f2bf(acc[i][j][3] + bvv);
        *(ushort4*)(out + (size_t)(bb * NH + h) * (SKL * DH) + chunk * 4096 +
                    (g * 4 + dsub) * 512 + (q4v * 16 + l15b) * 8 + half * 4) = pk;
      }
    }
  }
}

// ---------------- fused flash attention v7.1: ga=4 + truncation pack ----------------
// Delta vs round-10 green: P pack drops the +0x8000 round-to-nearest adds
// (truncate to bf16). Saves 2 VALU per 2 values (~2048 ops/wave) ON the
// exp->pack->A8->PV critical dependency chain. P in (0,1], trunc bias
// <= 2^-8 relative; osum is computed from the SAME truncated P so the
// output ratio self-normalizes. Expected absmax ~6e-4..1.2e-3 (thr 2.44e-3).
__global__ __launch_bounds__(256, 2) void attn_kernel(
    const unsigned short* __restrict__ Qb,  // [64][2048][64] bf16 (pre-scaled)
    const unsigned short* __restrict__ Kf,  // [64][32][4096] frag-major
    const unsigned short* __restrict__ Vf,  // [64][32][4096] frag-major
    const unsigned int* __restrict__ mw,    // [8192 rows][32 chunks][32 words]
    float* __restrict__ out) {              // [4][2048][1024]
  __shared__ short Ls[2 * 8192];  // [buf][K 4096 | V 4096]
  const int tid = threadIdx.x;
  const int wave = tid >> 6, lane = tid & 63;
  const int l15 = lane & 15, q4 = lane >> 4;
  // XCD-bijective swizzle: each XCD owns 8 whole bh's
  const int id = blockIdx.y * 8 + blockIdx.x;   // 512 blocks
  const int xcd = id & 7, idx = id >> 3;        // idx in [0,64)
  const int bh = xcd * 8 + (idx >> 3);
  const int b = bh >> 4, h = bh & 15;
  const int q0 = (idx & 7) * 256 + wave * 64;   // 64 rows per wave

  bf16x8 qa0[4], qa1[4];
#pragma unroll
  for (int ga = 0; ga < 4; ga++) {
    const unsigned short* qg = Qb + (size_t)(bh * SQL + q0 + ga * 16 + l15) * DH + q4 * 8;
    qa0[ga] = *(const bf16x8*)qg;
    qa1[ga] = *(const bf16x8*)(qg + 32);
  }

  f32x4 o[4][4], osum[4];
#pragma unroll
  for (int ga = 0; ga < 4; ga++) {
    osum[ga] = (f32x4){0.f, 0.f, 0.f, 0.f};
#pragma unroll
    for (int d = 0; d < 4; d++) o[ga][d] = (f32x4){0.f, 0.f, 0.f, 0.f};
  }
  uint4 onesu = {0x3f803f80u, 0x3f803f80u, 0x3f803f80u, 0x3f803f80u};
  const bf16x8 ones8 = __builtin_bit_cast(bf16x8, onesu);

  const unsigned short* kg = Kf + (size_t)bh * (SKL * DH);
  const unsigned short* vg = Vf + (size_t)bh * (SKL * DH);
  const unsigned int* mq[4];
#pragma unroll
  for (int ga = 0; ga < 4; ga++)
    mq[ga] = mw + (size_t)(b * SQL + q0 + ga * 16 + l15) * 1024 + q4 * 8;

  // stage chunk 0 into buf 0
  gld16(kg + tid * 8, Ls + tid * 8);
  gld16(kg + 2048 + tid * 8, Ls + 2048 + tid * 8);
  gld16(vg + tid * 8, Ls + 4096 + tid * 8);
  gld16(vg + 2048 + tid * 8, Ls + 6144 + tid * 8);
  __syncthreads();

  for (int cch = 0; cch < 32; cch++) {
    const int buf = cch & 1;
    // mask loads FIRST (so waiting on them doesn't drain the prefetch)
    uint4 mA[4], mB[4];
#pragma unroll
    for (int ga = 0; ga < 4; ga++) {
      const unsigned int* mp = mq[ga] + cch * 32;
      mA[ga] = *(const uint4*)mp;       // subs 0,1 (g=0)
      mB[ga] = *(const uint4*)(mp + 4); // subs 2,3 (g=1)
    }
    if (cch < 31) {
      const unsigned short* ks = kg + (size_t)(cch + 1) * 4096;
      const unsigned short* vs = vg + (size_t)(cch + 1) * 4096;
      short* db = Ls + (buf ^ 1) * 8192;
      gld16(ks + tid * 8, db + tid * 8);
      gld16(ks + 2048 + tid * 8, db + 2048 + tid * 8);
      gld16(vs + tid * 8, db + 4096 + tid * 8);
      gld16(vs + 2048 + tid * 8, db + 6144 + tid * 8);
    }

    const short* Kls = Ls + buf * 8192;
    const short* Vls = Kls + 4096;

#pragma unroll
    for (int g = 0; g < 2; g++) {
      uint2 pp[4][2];  // [ga][si]
#pragma unroll
      for (int si = 0; si < 2; si++) {
        const int sub = g * 2 + si;
        bf16x8 afA = *(const bf16x8*)(Kls + sub * 1024 + lane * 8);
        bf16x8 afB = *(const bf16x8*)(Kls + sub * 1024 + 512 + lane * 8);
#pragma unroll
        for (int ga = 0; ga < 4; ga++) {
          f32x4 s4 = (f32x4){0.f, 0.f, 0.f, 0.f};
          s4 = __builtin_amdgcn_mfma_f32_16x16x32_bf16(afA, qa0[ga], s4, 0, 0, 0);
          s4 = __builtin_amdgcn_mfma_f32_16x16x32_bf16(afB, qa1[ga], s4, 0, 0, 0);
          const uint4 msk = g ? mB[ga] : mA[ga];
          const unsigned int wlo = si ? msk.z : msk.x;
          const unsigned int whi = si ? msk.w : msk.y;
          union { float f; uint32_t u; } e0, e1, e2, e3;
          e0.f = __builtin_amdgcn_exp2f(s4[0]);
          e1.f = __builtin_amdgcn_exp2f(s4[1]);
          e2.f = __builtin_amdgcn_exp2f(s4[2]);
          e3.f = __builtin_amdgcn_exp2f(s4[3]);
          // truncation pack (no +0x8000 rounding): 3 ops/2 vals vs 5
          pp[ga][si].x = ((e0.u >> 16) | (e1.u & 0xffff0000u)) & wlo;
          pp[ga][si].y = ((e2.u >> 16) | (e3.u & 0xffff0000u)) & whi;
        }
      }
      bf16x8 A8[4];
#pragma unroll
      for (int ga = 0; ga < 4; ga++) {
        uint4 au = {pp[ga][0].x, pp[ga][0].y, pp[ga][1].x, pp[ga][1].y};
        A8[ga] = __builtin_bit_cast(bf16x8, au);
      }
      bf16x8 vf[4];
#pragma unroll
      for (int dsub = 0; dsub < 4; dsub++)
        vf[dsub] = *(const bf16x8*)(Vls + (g * 4 + dsub) * 512 + lane * 8);
      __builtin_amdgcn_s_setprio(1);
#pragma unroll
      for (int ga = 0; ga < 4; ga++) {
#pragma unroll
        for (int dsub = 0; dsub < 4; dsub++)
          o[ga][dsub] = __builtin_amdgcn_mfma_f32_16x16x32_bf16(A8[ga], vf[dsub], o[ga][dsub], 0, 0, 0);
        osum[ga] = __builtin_amdgcn_mfma_f32_16x16x32_bf16(A8[ga], ones8, osum[ga], 0, 0, 0);
      }
      __builtin_amdgcn_s_setprio(0);
    }
    __syncthreads();
  }

#pragma unroll
  for (int ga = 0; ga < 4; ga++)
#pragma unroll
    for (int rg = 0; rg < 4; rg++) {
      const float inv = 1.0f / osum[ga][rg];
      float* op = out + (size_t)(b * SQL + q0 + ga * 16 + q4 * 4 + rg) * 1024 + h * DH + l15;
#pragma unroll
      for (int dsub = 0; dsub < 4; dsub++) op[dsub * 16] = o[ga][dsub][rg] * inv;
    }
}

extern "C" void kernel_launch(void* const* d_in, const int* in_sizes, int n_in,
                              void* d_out, int out_size, void* d_ws, size_t ws_size,
                              hipStream_t stream) {
  const float* x_q  = (const float*)d_in[0];
  const float* x_kv = (const float*)d_in[1];
  const int*   amask = (const int*)d_in[2];
  const float* w_q  = (const float*)d_in[3];
  const float* b_q  = (const float*)d_in[4];
  const float* w_k  = (const float*)d_in[5];
  const float* b_k  = (const float*)d_in[6];
  const float* w_v  = (const float*)d_in[7];
  const float* b_v  = (const float*)d_in[8];
  float* out = (float*)d_out;

  char* ws = (char*)d_ws;
  // Phase 1 (dead after proj)
  unsigned short* xq_bf  = (unsigned short*)(ws + 0);          // 16 MB
  unsigned short* xkv_bf = (unsigned short*)(ws + 16777216);   // 16 MB
  unsigned short* wqt    = (unsigned short*)(ws + 33554432);   // 2 MB
  unsigned short* wkt    = (unsigned short*)(ws + 35651584);   // 2 MB
  unsigned short* wvt    = (unsigned short*)(ws + 37748736);   // 2 MB
  // Phase 2 (live into attn)
  unsigned short* Qb     = (unsigned short*)(ws + 39845888);   // 16 MB
  unsigned short* Kfb    = (unsigned short*)(ws + 56623104);   // 16 MB
  unsigned short* Vfb    = (unsigned short*)(ws + 73400320);   // 16 MB
  // mask written AFTER proj, overlaying dead phase-1 region
  unsigned int*   M32    = (unsigned int*)(ws + 0);            // 32 MB

  prep_kernel<<<19456, 256, 0, stream>>>(x_q, x_kv, xq_bf, xkv_bf,
                                         w_q, w_k, w_v, wqt, wkt, wvt);
  proj_gemm_kernel<<<dim3(8, 64, 3), 256, 0, stream>>>(
      xq_bf, xkv_bf, wqt, wkt, wvt, b_q, b_k, b_v, Qb, Kfb, Vfb);
  maskf_kernel<<<32768, 256, 0, stream>>>(amask, M32);
  attn_kernel<<<dim3(8, 64), 256, 0, stream>>>(Qb, Kfb, Vfb, M32, out);
}

// Round 13
// 328.507 us; speedup vs baseline: 1.0329x; 1.0063x over previous
//
#include <hip/hip_runtime.h>
#include <hip/hip_bf16.h>
#include <stdint.h>

#define BB 4
#define SQL 2048
#define SKL 2048
#define EMB 1024
#define NH 16
#define DH 64

typedef __bf16 bf16x8 __attribute__((ext_vector_type(8)));
typedef float f32x4 __attribute__((ext_vector_type(4)));

// scale folded into Q projection: 1/sqrt(64) * log2(e)
#define QSCALE 0.1803368801111144f

__device__ __forceinline__ unsigned short f2bf(float f) {
  union { float f; uint32_t u; } v; v.f = f;
  uint32_t u = v.u;
  return (unsigned short)((u + 0x7fffu + ((u >> 16) & 1u)) >> 16);
}

typedef const __attribute__((address_space(1))) void* gas_t;
typedef __attribute__((address_space(3))) void* las_t;
__device__ __forceinline__ void gld16(const void* g, void* l) {
  __builtin_amdgcn_global_load_lds((gas_t)g, (las_t)l, 16, 0, 0);
}

// ---------------- fused preprocessing: cvt(x_q) + cvt(x_kv) + wtrans x3 ----
// Blocks [0,8192): x_q cvt. [8192,16384): x_kv cvt. [16384,19456): wtrans.
__global__ void prep_kernel(const float* __restrict__ x_q, const float* __restrict__ x_kv,
                            unsigned short* __restrict__ xq_bf, unsigned short* __restrict__ xkv_bf,
                            const float* __restrict__ w0, const float* __restrict__ w1,
                            const float* __restrict__ w2,
                            unsigned short* __restrict__ o0, unsigned short* __restrict__ o1,
                            unsigned short* __restrict__ o2) {
  __shared__ float t[32][33];
  const int bid = blockIdx.x;
  if (bid < 16384) {
    const float* src = (bid < 8192) ? x_q : x_kv;
    unsigned short* dst = (bid < 8192) ? xq_bf : xkv_bf;
    int i = (bid & 8191) * 256 + threadIdx.x;
    float4 v = ((const float4*)src)[i];
    ushort4 o;
    o.x = f2bf(v.x); o.y = f2bf(v.y); o.z = f2bf(v.z); o.w = f2bf(v.w);
    ((ushort4*)dst)[i] = o;
    return;
  }
  // wtrans: w [K][N] fp32 -> w^T [N][K] bf16
  const int wb = bid - 16384;
  const int bx = wb & 31, by = (wb >> 5) & 31, bz = wb >> 10;
  const float* w = bz == 0 ? w0 : (bz == 1 ? w1 : w2);
  unsigned short* o = bz == 0 ? o0 : (bz == 1 ? o1 : o2);
  int tx = threadIdx.x & 31, ty = threadIdx.x >> 5;
  int n0 = bx * 32, k0 = by * 32;
#pragma unroll
  for (int r = 0; r < 4; r++)
    t[ty + r * 8][tx] = w[(size_t)(k0 + ty + r * 8) * EMB + n0 + tx];
  __syncthreads();
#pragma unroll
  for (int r = 0; r < 4; r++)
    o[(size_t)(n0 + ty + r * 8) * EMB + k0 + tx] = f2bf(t[tx][ty + r * 8]);
}

// ---------------- mask -> permuted halfword AND-masks (coalesced) ----------------
__global__ void maskf_kernel(const int* __restrict__ m, unsigned int* __restrict__ w) {
  unsigned int W = blockIdx.x * 256 + threadIdx.x;  // 8192*1024 words
  unsigned int row = W >> 10;
  unsigned int chunk = (W >> 5) & 31;
  unsigned int idx = W & 31;
  unsigned int q4 = idx >> 3, sub = (idx >> 1) & 3, pair = idx & 1;
  unsigned int kv = chunk * 64 + sub * 16 + q4 * 4 + pair * 2;
  int2 mm = *(const int2*)(m + (size_t)row * 2048 + kv);
  w[W] = (mm.x ? 0u : 0xffffu) | (mm.y ? 0u : 0xffff0000u);
}

// ---------------- fused projection GEMMs (z = 0:Q, 1:K, 2:V) ----------------
// round-10 green (BK=64, 2-phase): best measured proj config.
__global__ __launch_bounds__(256, 3) void proj_gemm_kernel(
    const unsigned short* __restrict__ Aq, const unsigned short* __restrict__ Akv,
    const unsigned short* __restrict__ W0, const unsigned short* __restrict__ W1,
    const unsigned short* __restrict__ W2,
    const float* __restrict__ bq, const float* __restrict__ bk, const float* __restrict__ bv,
    unsigned short* __restrict__ Oq, unsigned short* __restrict__ Ok,
    unsigned short* __restrict__ Ov) {
  __shared__ short As[128 * 64];  // [128 rows][64 cols] bf16, 16 KB
  __shared__ short Bs[128 * 64];
  const int z = blockIdx.z;
  const unsigned short* A = (z == 0) ? Aq : Akv;
  const unsigned short* Bt = (z == 0) ? W0 : (z == 1 ? W1 : W2);
  const float* bias = (z == 0) ? bq : (z == 1 ? bk : bv);
  unsigned short* out = (z == 0) ? Oq : (z == 1 ? Ok : Ov);
  const float oscale = (z == 0) ? QSCALE : 1.0f;

  const int tid = threadIdx.x;
  const int wave = tid >> 6, lane = tid & 63;
  const int l15 = lane & 15, q4 = lane >> 4;
  const int wm = wave >> 1, wn = wave & 1;
  const int m0 = blockIdx.y * 128, n0 = blockIdx.x * 128;

  f32x4 acc[4][4];
#pragma unroll
  for (int i = 0; i < 4; i++)
#pragma unroll
    for (int j = 0; j < 4; j++) acc[i][j] = (f32x4){0.f, 0.f, 0.f, 0.f};

  const int r = tid >> 3;
  const int c = (tid & 7) * 8;
  const unsigned short* gA = A + (size_t)(m0 + r) * EMB + c;
  const unsigned short* gB = Bt + (size_t)(n0 + r) * EMB + c;
  short* lA = As + tid * 8;
  short* lB = Bs + tid * 8;

  for (int kt = 0; kt < EMB / 64; kt++) {
    __syncthreads();
#pragma unroll
    for (int p = 0; p < 4; p++) {
      gld16(gA + (size_t)p * 32 * EMB + kt * 64, lA + p * 2048);
      gld16(gB + (size_t)p * 32 * EMB + kt * 64, lB + p * 2048);
    }
    __syncthreads();
#pragma unroll
    for (int kk = 0; kk < 2; kk++) {
      bf16x8 a[4], b[4];
#pragma unroll
      for (int i = 0; i < 4; i++)
        a[i] = *(const bf16x8*)(As + (wm * 64 + i * 16 + l15) * 64 + kk * 32 + q4 * 8);
#pragma unroll
      for (int j = 0; j < 4; j++)
        b[j] = *(const bf16x8*)(Bs + (wn * 64 + j * 16 + l15) * 64 + kk * 32 + q4 * 8);
#pragma unroll
      for (int i = 0; i < 4; i++)
#pragma unroll
        for (int j = 0; j < 4; j++)
          acc[i][j] = __builtin_amdgcn_mfma_f32_16x16x32_bf16(a[i], b[j], acc[i][j], 0, 0, 0);
    }
  }

#pragma unroll
  for (int i = 0; i < 4; i++) {
    const int mrow = m0 + wm * 64 + i * 16 + q4 * 4;
#pragma unroll
    for (int j = 0; j < 4; j++) {
      const int n = n0 + wn * 64 + j * 16 + l15;
      const float bvv = bias[n];
      const int h = n >> 6, d = n & 63;
      const int bb = mrow >> 11, sq = mrow & 2047;
      if (z == 0) {
#pragma unroll
        for (int rg = 0; rg < 4; rg++)
          out[(size_t)((bb * NH + h) * SQL + sq + rg) * DH + d] =
              f2bf((acc[i][j][rg] + bvv) * oscale);
      } else if (z == 1) {
        const int chunk = sq >> 6, subK = (sq >> 4) & 3, l15k = sq & 15;
        const int halfd = d >> 5, q4k = (d >> 3) & 3, jk = d & 7;
        unsigned short* base = out + (size_t)(bb * NH + h) * (SKL * DH) + chunk * 4096 +
                               (subK * 2 + halfd) * 512 + (q4k * 16 + l15k) * 8 + jk;
#pragma unroll
        for (int rg = 0; rg < 4; rg++) base[rg * 8] = f2bf(acc[i][j][rg] + bvv);
      } else {
        const int chunk = sq >> 6, g = (sq >> 5) & 1, half = (sq >> 4) & 1, q4v = (sq >> 2) & 3;
        const int dsub = d >> 4, l15b = d & 15;
        ushort4 pk;
        pk.x = f2bf(acc[i][j][0] + bvv);
        pk.y = f2bf(acc[i][j][1] + bvv);
        pk.z = f2bf(acc[i][j][2] + bvv);
        pk.w = f2bf(acc[i][j][3] + bvv);
        *(ushort4*)(out + (size_t)(bb * NH + h) * (SKL * DH) + chunk * 4096 +
                    (g * 4 + dsub) * 512 + (q4v * 16 + l15b) * 8 + half * 4) = pk;
      }
    }
  }
}

// ---------------- fused flash attention v8: KVBLK=128 (half the barriers) ----------------
// Round-12 showed attn is latency/sync-bound (VALU cut -> no speedup). 64
// all-wave barrier rendezvous (each = implicit vmcnt(0) drain + skew resync)
// remain the only un-attacked term. KVBLK 64->128: stage two 64-row chunks
// per outer iter (Ls = 2 x 32KB bufs = 64KB; 2 blocks/CU = 128KB <= 160),
// run the identical inner compute twice per barrier pair. Barriers 64->32;
// each drain now sits behind 2x compute. Masks for BOTH halves are loaded
// BEFORE the prefetch issue (in-order vmcnt: mask waits never drain the
// prefetch). All mask indices static (rule #20 safe).
__global__ __launch_bounds__(256, 2) void attn_kernel(
    const unsigned short* __restrict__ Qb,  // [64][2048][64] bf16 (pre-scaled)
    const unsigned short* __restrict__ Kf,  // [64][32][4096] frag-major
    const unsigned short* __restrict__ Vf,  // [64][32][4096] frag-major
    const unsigned int* __restrict__ mw,    // [8192 rows][32 chunks][32 words]
    float* __restrict__ out) {              // [4][2048][1024]
  __shared__ short Ls[2 * 16384];  // [buf][half][K 4096 | V 4096] = 64 KB
  const int tid = threadIdx.x;
  const int wave = tid >> 6, lane = tid & 63;
  const int l15 = lane & 15, q4 = lane >> 4;
  // XCD-bijective swizzle: each XCD owns 8 whole bh's
  const int id = blockIdx.y * 8 + blockIdx.x;   // 512 blocks
  const int xcd = id & 7, idx = id >> 3;        // idx in [0,64)
  const int bh = xcd * 8 + (idx >> 3);
  const int b = bh >> 4, h = bh & 15;
  const int q0 = (idx & 7) * 256 + wave * 64;   // 64 rows per wave

  bf16x8 qa0[4], qa1[4];
#pragma unroll
  for (int ga = 0; ga < 4; ga++) {
    const unsigned short* qg = Qb + (size_t)(bh * SQL + q0 + ga * 16 + l15) * DH + q4 * 8;
    qa0[ga] = *(const bf16x8*)qg;
    qa1[ga] = *(const bf16x8*)(qg + 32);
  }

  f32x4 o[4][4], osum[4];
#pragma unroll
  for (int ga = 0; ga < 4; ga++) {
    osum[ga] = (f32x4){0.f, 0.f, 0.f, 0.f};
#pragma unroll
    for (int d = 0; d < 4; d++) o[ga][d] = (f32x4){0.f, 0.f, 0.f, 0.f};
  }
  uint4 onesu = {0x3f803f80u, 0x3f803f80u, 0x3f803f80u, 0x3f803f80u};
  const bf16x8 ones8 = __builtin_bit_cast(bf16x8, onesu);

  const unsigned short* kg = Kf + (size_t)bh * (SKL * DH);
  const unsigned short* vg = Vf + (size_t)bh * (SKL * DH);
  const unsigned int* mq[4];
#pragma unroll
  for (int ga = 0; ga < 4; ga++)
    mq[ga] = mw + (size_t)(b * SQL + q0 + ga * 16 + l15) * 1024 + q4 * 8;

  // prologue: stage big-chunk 0 (kv chunks 0,1) into buf 0
#pragma unroll
  for (int h2 = 0; h2 < 2; h2++) {
    gld16(kg + h2 * 4096 + tid * 8, Ls + h2 * 8192 + tid * 8);
    gld16(kg + h2 * 4096 + 2048 + tid * 8, Ls + h2 * 8192 + 2048 + tid * 8);
    gld16(vg + h2 * 4096 + tid * 8, Ls + h2 * 8192 + 4096 + tid * 8);
    gld16(vg + h2 * 4096 + 2048 + tid * 8, Ls + h2 * 8192 + 6144 + tid * 8);
  }
  __syncthreads();

  for (int big = 0; big < 16; big++) {
    const int buf = big & 1;
    // masks for BOTH halves FIRST (older than prefetch in vmcnt order)
    uint4 mA[2][4], mB[2][4];
#pragma unroll
    for (int hf = 0; hf < 2; hf++)
#pragma unroll
      for (int ga = 0; ga < 4; ga++) {
        const unsigned int* mp = mq[ga] + (big * 2 + hf) * 32;
        mA[hf][ga] = *(const uint4*)mp;       // subs 0,1 (g=0)
        mB[hf][ga] = *(const uint4*)(mp + 4); // subs 2,3 (g=1)
      }
    if (big < 15) {
      const unsigned short* ks = kg + (size_t)(big + 1) * 8192;
      const unsigned short* vs = vg + (size_t)(big + 1) * 8192;
      short* db = Ls + (buf ^ 1) * 16384;
#pragma unroll
      for (int h2 = 0; h2 < 2; h2++) {
        gld16(ks + h2 * 4096 + tid * 8, db + h2 * 8192 + tid * 8);
        gld16(ks + h2 * 4096 + 2048 + tid * 8, db + h2 * 8192 + 2048 + tid * 8);
        gld16(vs + h2 * 4096 + tid * 8, db + h2 * 8192 + 4096 + tid * 8);
        gld16(vs + h2 * 4096 + 2048 + tid * 8, db + h2 * 8192 + 6144 + tid * 8);
      }
    }

#pragma unroll
    for (int hf = 0; hf < 2; hf++) {
      const short* Kls = Ls + buf * 16384 + hf * 8192;
      const short* Vls = Kls + 4096;

#pragma unroll
      for (int g = 0; g < 2; g++) {
        uint2 pp[4][2];  // [ga][si]
#pragma unroll
        for (int si = 0; si < 2; si++) {
          const int sub = g * 2 + si;
          bf16x8 afA = *(const bf16x8*)(Kls + sub * 1024 + lane * 8);
          bf16x8 afB = *(const bf16x8*)(Kls + sub * 1024 + 512 + lane * 8);
#pragma unroll
          for (int ga = 0; ga < 4; ga++) {
            f32x4 s4 = (f32x4){0.f, 0.f, 0.f, 0.f};
            s4 = __builtin_amdgcn_mfma_f32_16x16x32_bf16(afA, qa0[ga], s4, 0, 0, 0);
            s4 = __builtin_amdgcn_mfma_f32_16x16x32_bf16(afB, qa1[ga], s4, 0, 0, 0);
            const uint4 msk = g ? mB[hf][ga] : mA[hf][ga];
            const unsigned int wlo = si ? msk.z : msk.x;
            const unsigned int whi = si ? msk.w : msk.y;
            union { float f; uint32_t u; } e0, e1, e2, e3;
            e0.f = __builtin_amdgcn_exp2f(s4[0]);
            e1.f = __builtin_amdgcn_exp2f(s4[1]);
            e2.f = __builtin_amdgcn_exp2f(s4[2]);
            e3.f = __builtin_amdgcn_exp2f(s4[3]);
            // truncation pack (round-12 green)
            pp[ga][si].x = ((e0.u >> 16) | (e1.u & 0xffff0000u)) & wlo;
            pp[ga][si].y = ((e2.u >> 16) | (e3.u & 0xffff0000u)) & whi;
          }
        }
        bf16x8 A8[4];
#pragma unroll
        for (int ga = 0; ga < 4; ga++) {
          uint4 au = {pp[ga][0].x, pp[ga][0].y, pp[ga][1].x, pp[ga][1].y};
          A8[ga] = __builtin_bit_cast(bf16x8, au);
        }
        bf16x8 vf[4];
#pragma unroll
        for (int dsub = 0; dsub < 4; dsub++)
          vf[dsub] = *(const bf16x8*)(Vls + (g * 4 + dsub) * 512 + lane * 8);
        __builtin_amdgcn_s_setprio(1);
#pragma unroll
        for (int ga = 0; ga < 4; ga++) {
#pragma unroll
          for (int dsub = 0; dsub < 4; dsub++)
            o[ga][dsub] = __builtin_amdgcn_mfma_f32_16x16x32_bf16(A8[ga], vf[dsub], o[ga][dsub], 0, 0, 0);
          osum[ga] = __builtin_amdgcn_mfma_f32_16x16x32_bf16(A8[ga], ones8, osum[ga], 0, 0, 0);
        }
        __builtin_amdgcn_s_setprio(0);
      }
    }
    __syncthreads();
  }

#pragma unroll
  for (int ga = 0; ga < 4; ga++)
#pragma unroll
    for (int rg = 0; rg < 4; rg++) {
      const float inv = 1.0f / osum[ga][rg];
      float* op = out + (size_t)(b * SQL + q0 + ga * 16 + q4 * 4 + rg) * 1024 + h * DH + l15;
#pragma unroll
      for (int dsub = 0; dsub < 4; dsub++) op[dsub * 16] = o[ga][dsub][rg] * inv;
    }
}

extern "C" void kernel_launch(void* const* d_in, const int* in_sizes, int n_in,
                              void* d_out, int out_size, void* d_ws, size_t ws_size,
                              hipStream_t stream) {
  const float* x_q  = (const float*)d_in[0];
  const float* x_kv = (const float*)d_in[1];
  const int*   amask = (const int*)d_in[2];
  const float* w_q  = (const float*)d_in[3];
  const float* b_q  = (const float*)d_in[4];
  const float* w_k  = (const float*)d_in[5];
  const float* b_k  = (const float*)d_in[6];
  const float* w_v  = (const float*)d_in[7];
  const float* b_v  = (const float*)d_in[8];
  float* out = (float*)d_out;

  char* ws = (char*)d_ws;
  // Phase 1 (dead after proj)
  unsigned short* xq_bf  = (unsigned short*)(ws + 0);          // 16 MB
  unsigned short* xkv_bf = (unsigned short*)(ws + 16777216);   // 16 MB
  unsigned short* wqt    = (unsigned short*)(ws + 33554432);   // 2 MB
  unsigned short* wkt    = (unsigned short*)(ws + 35651584);   // 2 MB
  unsigned short* wvt    = (unsigned short*)(ws + 37748736);   // 2 MB
  // Phase 2 (live into attn)
  unsigned short* Qb     = (unsigned short*)(ws + 39845888);   // 16 MB
  unsigned short* Kfb    = (unsigned short*)(ws + 56623104);   // 16 MB
  unsigned short* Vfb    = (unsigned short*)(ws + 73400320);   // 16 MB
  // mask written AFTER proj, overlaying dead phase-1 region
  unsigned int*   M32    = (unsigned int*)(ws + 0);            // 32 MB

  prep_kernel<<<19456, 256, 0, stream>>>(x_q, x_kv, xq_bf, xkv_bf,
                                         w_q, w_k, w_v, wqt, wkt, wvt);
  proj_gemm_kernel<<<dim3(8, 64, 3), 256, 0, stream>>>(
      xq_bf, xkv_bf, wqt, wkt, wvt, b_q, b_k, b_v, Qb, Kfb, Vfb);
  maskf_kernel<<<32768, 256, 0, stream>>>(amask, M32);
  attn_kernel<<<dim3(8, 64), 256, 0, stream>>>(Qb, Kfb, Vfb, M32, out);
}

// Round 14
// 324.437 us; speedup vs baseline: 1.0458x; 1.0125x over previous
//
#include <hip/hip_runtime.h>
#include <hip/hip_bf16.h>
#include <stdint.h>

#define BB 4
#define SQL 2048
#define SKL 2048
#define EMB 1024
#define NH 16
#define DH 64

typedef __bf16 bf16x8 __attribute__((ext_vector_type(8)));
typedef float f32x4 __attribute__((ext_vector_type(4)));

// scale folded into Q projection: 1/sqrt(64) * log2(e)
#define QSCALE 0.1803368801111144f

__device__ __forceinline__ unsigned short f2bf(float f) {
  union { float f; uint32_t u; } v; v.f = f;
  uint32_t u = v.u;
  return (unsigned short)((u + 0x7fffu + ((u >> 16) & 1u)) >> 16);
}

typedef const __attribute__((address_space(1))) void* gas_t;
typedef __attribute__((address_space(3))) void* las_t;
__device__ __forceinline__ void gld16(const void* g, void* l) {
  __builtin_amdgcn_global_load_lds((gas_t)g, (las_t)l, 16, 0, 0);
}

__device__ __forceinline__ void maskf_body(const int* __restrict__ m,
                                           unsigned int* __restrict__ w,
                                           unsigned int W) {
  unsigned int row = W >> 10;
  unsigned int chunk = (W >> 5) & 31;
  unsigned int idx = W & 31;
  unsigned int q4 = idx >> 3, sub = (idx >> 1) & 3, pair = idx & 1;
  unsigned int kv = chunk * 64 + sub * 16 + q4 * 4 + pair * 2;
  int2 mm = *(const int2*)(m + (size_t)row * 2048 + kv);
  w[W] = (mm.x ? 0u : 0xffffu) | (mm.y ? 0u : 0xffff0000u);
}

// ---------------- fused preprocessing v2: cvt + wtrans + maskf ----------------
// Blocks [0,8192): x_q cvt. [8192,16384): x_kv cvt. [16384,19456): wtrans.
// [19456,52224): maskf (independent root of the DAG -- fusing removes one
// serial launch gap and overlaps its BW work with prep's ramp tail).
__global__ void prep_mask_kernel(const float* __restrict__ x_q, const float* __restrict__ x_kv,
                                 unsigned short* __restrict__ xq_bf, unsigned short* __restrict__ xkv_bf,
                                 const float* __restrict__ w0, const float* __restrict__ w1,
                                 const float* __restrict__ w2,
                                 unsigned short* __restrict__ o0, unsigned short* __restrict__ o1,
                                 unsigned short* __restrict__ o2,
                                 const int* __restrict__ m, unsigned int* __restrict__ mwout) {
  __shared__ float t[32][33];
  const int bid = blockIdx.x;
  if (bid < 16384) {
    const float* src = (bid < 8192) ? x_q : x_kv;
    unsigned short* dst = (bid < 8192) ? xq_bf : xkv_bf;
    int i = (bid & 8191) * 256 + threadIdx.x;
    float4 v = ((const float4*)src)[i];
    ushort4 o;
    o.x = f2bf(v.x); o.y = f2bf(v.y); o.z = f2bf(v.z); o.w = f2bf(v.w);
    ((ushort4*)dst)[i] = o;
    return;
  }
  if (bid >= 19456) {
    maskf_body(m, mwout, (unsigned int)(bid - 19456) * 256 + threadIdx.x);
    return;
  }
  // wtrans: w [K][N] fp32 -> w^T [N][K] bf16
  const int wb = bid - 16384;
  const int bx = wb & 31, by = (wb >> 5) & 31, bz = wb >> 10;
  const float* w = bz == 0 ? w0 : (bz == 1 ? w1 : w2);
  unsigned short* o = bz == 0 ? o0 : (bz == 1 ? o1 : o2);
  int tx = threadIdx.x & 31, ty = threadIdx.x >> 5;
  int n0 = bx * 32, k0 = by * 32;
#pragma unroll
  for (int r = 0; r < 4; r++)
    t[ty + r * 8][tx] = w[(size_t)(k0 + ty + r * 8) * EMB + n0 + tx];
  __syncthreads();
#pragma unroll
  for (int r = 0; r < 4; r++)
    o[(size_t)(n0 + ty + r * 8) * EMB + k0 + tx] = f2bf(t[tx][ty + r * 8]);
}

// ---------------- legacy split kernels (fallback when ws too small) ----------
__global__ void prep_kernel(const float* __restrict__ x_q, const float* __restrict__ x_kv,
                            unsigned short* __restrict__ xq_bf, unsigned short* __restrict__ xkv_bf,
                            const float* __restrict__ w0, const float* __restrict__ w1,
                            const float* __restrict__ w2,
                            unsigned short* __restrict__ o0, unsigned short* __restrict__ o1,
                            unsigned short* __restrict__ o2) {
  __shared__ float t[32][33];
  const int bid = blockIdx.x;
  if (bid < 16384) {
    const float* src = (bid < 8192) ? x_q : x_kv;
    unsigned short* dst = (bid < 8192) ? xq_bf : xkv_bf;
    int i = (bid & 8191) * 256 + threadIdx.x;
    float4 v = ((const float4*)src)[i];
    ushort4 o;
    o.x = f2bf(v.x); o.y = f2bf(v.y); o.z = f2bf(v.z); o.w = f2bf(v.w);
    ((ushort4*)dst)[i] = o;
    return;
  }
  const int wb = bid - 16384;
  const int bx = wb & 31, by = (wb >> 5) & 31, bz = wb >> 10;
  const float* w = bz == 0 ? w0 : (bz == 1 ? w1 : w2);
  unsigned short* o = bz == 0 ? o0 : (bz == 1 ? o1 : o2);
  int tx = threadIdx.x & 31, ty = threadIdx.x >> 5;
  int n0 = bx * 32, k0 = by * 32;
#pragma unroll
  for (int r = 0; r < 4; r++)
    t[ty + r * 8][tx] = w[(size_t)(k0 + ty + r * 8) * EMB + n0 + tx];
  __syncthreads();
#pragma unroll
  for (int r = 0; r < 4; r++)
    o[(size_t)(n0 + ty + r * 8) * EMB + k0 + tx] = f2bf(t[tx][ty + r * 8]);
}

__global__ void maskf_kernel(const int* __restrict__ m, unsigned int* __restrict__ w) {
  maskf_body(m, w, blockIdx.x * 256 + threadIdx.x);
}

// ---------------- fused projection GEMMs (z = 0:Q, 1:K, 2:V) ----------------
// round-10 green (BK=64, 2-phase): best measured proj config.
__global__ __launch_bounds__(256, 3) void proj_gemm_kernel(
    const unsigned short* __restrict__ Aq, const unsigned short* __restrict__ Akv,
    const unsigned short* __restrict__ W0, const unsigned short* __restrict__ W1,
    const unsigned short* __restrict__ W2,
    const float* __restrict__ bq, const float* __restrict__ bk, const float* __restrict__ bv,
    unsigned short* __restrict__ Oq, unsigned short* __restrict__ Ok,
    unsigned short* __restrict__ Ov) {
  __shared__ short As[128 * 64];  // [128 rows][64 cols] bf16, 16 KB
  __shared__ short Bs[128 * 64];
  const int z = blockIdx.z;
  const unsigned short* A = (z == 0) ? Aq : Akv;
  const unsigned short* Bt = (z == 0) ? W0 : (z == 1 ? W1 : W2);
  const float* bias = (z == 0) ? bq : (z == 1 ? bk : bv);
  unsigned short* out = (z == 0) ? Oq : (z == 1 ? Ok : Ov);
  const float oscale = (z == 0) ? QSCALE : 1.0f;

  const int tid = threadIdx.x;
  const int wave = tid >> 6, lane = tid & 63;
  const int l15 = lane & 15, q4 = lane >> 4;
  const int wm = wave >> 1, wn = wave & 1;
  const int m0 = blockIdx.y * 128, n0 = blockIdx.x * 128;

  f32x4 acc[4][4];
#pragma unroll
  for (int i = 0; i < 4; i++)
#pragma unroll
    for (int j = 0; j < 4; j++) acc[i][j] = (f32x4){0.f, 0.f, 0.f, 0.f};

  const int r = tid >> 3;
  const int c = (tid & 7) * 8;
  const unsigned short* gA = A + (size_t)(m0 + r) * EMB + c;
  const unsigned short* gB = Bt + (size_t)(n0 + r) * EMB + c;
  short* lA = As + tid * 8;
  short* lB = Bs + tid * 8;

  for (int kt = 0; kt < EMB / 64; kt++) {
    __syncthreads();
#pragma unroll
    for (int p = 0; p < 4; p++) {
      gld16(gA + (size_t)p * 32 * EMB + kt * 64, lA + p * 2048);
      gld16(gB + (size_t)p * 32 * EMB + kt * 64, lB + p * 2048);
    }
    __syncthreads();
#pragma unroll
    for (int kk = 0; kk < 2; kk++) {
      bf16x8 a[4], b[4];
#pragma unroll
      for (int i = 0; i < 4; i++)
        a[i] = *(const bf16x8*)(As + (wm * 64 + i * 16 + l15) * 64 + kk * 32 + q4 * 8);
#pragma unroll
      for (int j = 0; j < 4; j++)
        b[j] = *(const bf16x8*)(Bs + (wn * 64 + j * 16 + l15) * 64 + kk * 32 + q4 * 8);
#pragma unroll
      for (int i = 0; i < 4; i++)
#pragma unroll
        for (int j = 0; j < 4; j++)
          acc[i][j] = __builtin_amdgcn_mfma_f32_16x16x32_bf16(a[i], b[j], acc[i][j], 0, 0, 0);
    }
  }

#pragma unroll
  for (int i = 0; i < 4; i++) {
    const int mrow = m0 + wm * 64 + i * 16 + q4 * 4;
#pragma unroll
    for (int j = 0; j < 4; j++) {
      const int n = n0 + wn * 64 + j * 16 + l15;
      const float bvv = bias[n];
      const int h = n >> 6, d = n & 63;
      const int bb = mrow >> 11, sq = mrow & 2047;
      if (z == 0) {
#pragma unroll
        for (int rg = 0; rg < 4; rg++)
          out[(size_t)((bb * NH + h) * SQL + sq + rg) * DH + d] =
              f2bf((acc[i][j][rg] + bvv) * oscale);
      } else if (z == 1) {
        const int chunk = sq >> 6, subK = (sq >> 4) & 3, l15k = sq & 15;
        const int halfd = d >> 5, q4k = (d >> 3) & 3, jk = d & 7;
        unsigned short* base = out + (size_t)(bb * NH + h) * (SKL * DH) + chunk * 4096 +
                               (subK * 2 + halfd) * 512 + (q4k * 16 + l15k) * 8 + jk;
#pragma unroll
        for (int rg = 0; rg < 4; rg++) base[rg * 8] = f2bf(acc[i][j][rg] + bvv);
      } else {
        const int chunk = sq >> 6, g = (sq >> 5) & 1, half = (sq >> 4) & 1, q4v = (sq >> 2) & 3;
        const int dsub = d >> 4, l15b = d & 15;
        ushort4 pk;
        pk.x = f2bf(acc[i][j][0] + bvv);
        pk.y = f2bf(acc[i][j][1] + bvv);
        pk.z = f2bf(acc[i][j][2] + bvv);
        pk.w = f2bf(acc[i][j][3] + bvv);
        *(ushort4*)(out + (size_t)(bb * NH + h) * (SKL * DH) + chunk * 4096 +
                    (g * 4 + dsub) * 512 + (q4v * 16 + l15b) * 8 + half * 4) = pk;
      }
    }
  }
}

// ---------------- fused flash attention v8: KVBLK=128 (round-13 green) ----------------
__global__ __launch_bounds__(256, 2) void attn_kernel(
    const unsigned short* __restrict__ Qb,  // [64][2048][64] bf16 (pre-scaled)
    const unsigned short* __restrict__ Kf,  // [64][32][4096] frag-major
    const unsigned short* __restrict__ Vf,  // [64][32][4096] frag-major
    const unsigned int* __restrict__ mw,    // [8192 rows][32 chunks][32 words]
    float* __restrict__ out) {              // [4][2048][1024]
  __shared__ short Ls[2 * 16384];  // [buf][half][K 4096 | V 4096] = 64 KB
  const int tid = threadIdx.x;
  const int wave = tid >> 6, lane = tid & 63;
  const int l15 = lane & 15, q4 = lane >> 4;
  // XCD-bijective swizzle: each XCD owns 8 whole bh's
  const int id = blockIdx.y * 8 + blockIdx.x;   // 512 blocks
  const int xcd = id & 7, idx = id >> 3;        // idx in [0,64)
  const int bh = xcd * 8 + (idx >> 3);
  const int b = bh >> 4, h = bh & 15;
  const int q0 = (idx & 7) * 256 + wave * 64;   // 64 rows per wave

  bf16x8 qa0[4], qa1[4];
#pragma unroll
  for (int ga = 0; ga < 4; ga++) {
    const unsigned short* qg = Qb + (size_t)(bh * SQL + q0 + ga * 16 + l15) * DH + q4 * 8;
    qa0[ga] = *(const bf16x8*)qg;
    qa1[ga] = *(const bf16x8*)(qg + 32);
  }

  f32x4 o[4][4], osum[4];
#pragma unroll
  for (int ga = 0; ga < 4; ga++) {
    osum[ga] = (f32x4){0.f, 0.f, 0.f, 0.f};
#pragma unroll
    for (int d = 0; d < 4; d++) o[ga][d] = (f32x4){0.f, 0.f, 0.f, 0.f};
  }
  uint4 onesu = {0x3f803f80u, 0x3f803f80u, 0x3f803f80u, 0x3f803f80u};
  const bf16x8 ones8 = __builtin_bit_cast(bf16x8, onesu);

  const unsigned short* kg = Kf + (size_t)bh * (SKL * DH);
  const unsigned short* vg = Vf + (size_t)bh * (SKL * DH);
  const unsigned int* mq[4];
#pragma unroll
  for (int ga = 0; ga < 4; ga++)
    mq[ga] = mw + (size_t)(b * SQL + q0 + ga * 16 + l15) * 1024 + q4 * 8;

  // prologue: stage big-chunk 0 (kv chunks 0,1) into buf 0
#pragma unroll
  for (int h2 = 0; h2 < 2; h2++) {
    gld16(kg + h2 * 4096 + tid * 8, Ls + h2 * 8192 + tid * 8);
    gld16(kg + h2 * 4096 + 2048 + tid * 8, Ls + h2 * 8192 + 2048 + tid * 8);
    gld16(vg + h2 * 4096 + tid * 8, Ls + h2 * 8192 + 4096 + tid * 8);
    gld16(vg + h2 * 4096 + 2048 + tid * 8, Ls + h2 * 8192 + 6144 + tid * 8);
  }
  __syncthreads();

  for (int big = 0; big < 16; big++) {
    const int buf = big & 1;
    // masks for BOTH halves FIRST (older than prefetch in vmcnt order)
    uint4 mA[2][4], mB[2][4];
#pragma unroll
    for (int hf = 0; hf < 2; hf++)
#pragma unroll
      for (int ga = 0; ga < 4; ga++) {
        const unsigned int* mp = mq[ga] + (big * 2 + hf) * 32;
        mA[hf][ga] = *(const uint4*)mp;       // subs 0,1 (g=0)
        mB[hf][ga] = *(const uint4*)(mp + 4); // subs 2,3 (g=1)
      }
    if (big < 15) {
      const unsigned short* ks = kg + (size_t)(big + 1) * 8192;
      const unsigned short* vs = vg + (size_t)(big + 1) * 8192;
      short* db = Ls + (buf ^ 1) * 16384;
#pragma unroll
      for (int h2 = 0; h2 < 2; h2++) {
        gld16(ks + h2 * 4096 + tid * 8, db + h2 * 8192 + tid * 8);
        gld16(ks + h2 * 4096 + 2048 + tid * 8, db + h2 * 8192 + 2048 + tid * 8);
        gld16(vs + h2 * 4096 + tid * 8, db + h2 * 8192 + 4096 + tid * 8);
        gld16(vs + h2 * 4096 + 2048 + tid * 8, db + h2 * 8192 + 6144 + tid * 8);
      }
    }

#pragma unroll
    for (int hf = 0; hf < 2; hf++) {
      const short* Kls = Ls + buf * 16384 + hf * 8192;
      const short* Vls = Kls + 4096;

#pragma unroll
      for (int g = 0; g < 2; g++) {
        uint2 pp[4][2];  // [ga][si]
#pragma unroll
        for (int si = 0; si < 2; si++) {
          const int sub = g * 2 + si;
          bf16x8 afA = *(const bf16x8*)(Kls + sub * 1024 + lane * 8);
          bf16x8 afB = *(const bf16x8*)(Kls + sub * 1024 + 512 + lane * 8);
#pragma unroll
          for (int ga = 0; ga < 4; ga++) {
            f32x4 s4 = (f32x4){0.f, 0.f, 0.f, 0.f};
            s4 = __builtin_amdgcn_mfma_f32_16x16x32_bf16(afA, qa0[ga], s4, 0, 0, 0);
            s4 = __builtin_amdgcn_mfma_f32_16x16x32_bf16(afB, qa1[ga], s4, 0, 0, 0);
            const uint4 msk = g ? mB[hf][ga] : mA[hf][ga];
            const unsigned int wlo = si ? msk.z : msk.x;
            const unsigned int whi = si ? msk.w : msk.y;
            union { float f; uint32_t u; } e0, e1, e2, e3;
            e0.f = __builtin_amdgcn_exp2f(s4[0]);
            e1.f = __builtin_amdgcn_exp2f(s4[1]);
            e2.f = __builtin_amdgcn_exp2f(s4[2]);
            e3.f = __builtin_amdgcn_exp2f(s4[3]);
            // truncation pack (round-12 green)
            pp[ga][si].x = ((e0.u >> 16) | (e1.u & 0xffff0000u)) & wlo;
            pp[ga][si].y = ((e2.u >> 16) | (e3.u & 0xffff0000u)) & whi;
          }
        }
        bf16x8 A8[4];
#pragma unroll
        for (int ga = 0; ga < 4; ga++) {
          uint4 au = {pp[ga][0].x, pp[ga][0].y, pp[ga][1].x, pp[ga][1].y};
          A8[ga] = __builtin_bit_cast(bf16x8, au);
        }
        bf16x8 vf[4];
#pragma unroll
        for (int dsub = 0; dsub < 4; dsub++)
          vf[dsub] = *(const bf16x8*)(Vls + (g * 4 + dsub) * 512 + lane * 8);
        __builtin_amdgcn_s_setprio(1);
#pragma unroll
        for (int ga = 0; ga < 4; ga++) {
#pragma unroll
          for (int dsub = 0; dsub < 4; dsub++)
            o[ga][dsub] = __builtin_amdgcn_mfma_f32_16x16x32_bf16(A8[ga], vf[dsub], o[ga][dsub], 0, 0, 0);
          osum[ga] = __builtin_amdgcn_mfma_f32_16x16x32_bf16(A8[ga], ones8, osum[ga], 0, 0, 0);
        }
        __builtin_amdgcn_s_setprio(0);
      }
    }
    __syncthreads();
  }

#pragma unroll
  for (int ga = 0; ga < 4; ga++)
#pragma unroll
    for (int rg = 0; rg < 4; rg++) {
      const float inv = 1.0f / osum[ga][rg];
      float* op = out + (size_t)(b * SQL + q0 + ga * 16 + q4 * 4 + rg) * 1024 + h * DH + l15;
#pragma unroll
      for (int dsub = 0; dsub < 4; dsub++) op[dsub * 16] = o[ga][dsub][rg] * inv;
    }
}

extern "C" void kernel_launch(void* const* d_in, const int* in_sizes, int n_in,
                              void* d_out, int out_size, void* d_ws, size_t ws_size,
                              hipStream_t stream) {
  const float* x_q  = (const float*)d_in[0];
  const float* x_kv = (const float*)d_in[1];
  const int*   amask = (const int*)d_in[2];
  const float* w_q  = (const float*)d_in[3];
  const float* b_q  = (const float*)d_in[4];
  const float* w_k  = (const float*)d_in[5];
  const float* b_k  = (const float*)d_in[6];
  const float* w_v  = (const float*)d_in[7];
  const float* b_v  = (const float*)d_in[8];
  float* out = (float*)d_out;

  char* ws = (char*)d_ws;
  // Phase 1 (dead after proj)
  unsigned short* xq_bf  = (unsigned short*)(ws + 0);          // 16 MB
  unsigned short* xkv_bf = (unsigned short*)(ws + 16777216);   // 16 MB
  unsigned short* wqt    = (unsigned short*)(ws + 33554432);   // 2 MB
  unsigned short* wkt    = (unsigned short*)(ws + 35651584);   // 2 MB
  unsigned short* wvt    = (unsigned short*)(ws + 37748736);   // 2 MB
  // Phase 2 (live into attn)
  unsigned short* Qb     = (unsigned short*)(ws + 39845888);   // 16 MB
  unsigned short* Kfb    = (unsigned short*)(ws + 56623104);   // 16 MB
  unsigned short* Vfb    = (unsigned short*)(ws + 73400320);   // 16 MB  (ends 90177536)

  if (ws_size >= (size_t)90177536 + 33554432) {
    // Fused path: maskf folded into prep (3 launches). M32 lives ABOVE Vfb
    // (it is written before proj now, so it cannot overlay phase-1 space).
    unsigned int* M32 = (unsigned int*)(ws + 90177536);        // 32 MB
    prep_mask_kernel<<<52224, 256, 0, stream>>>(x_q, x_kv, xq_bf, xkv_bf,
                                                w_q, w_k, w_v, wqt, wkt, wvt,
                                                amask, M32);
    proj_gemm_kernel<<<dim3(8, 64, 3), 256, 0, stream>>>(
        xq_bf, xkv_bf, wqt, wkt, wvt, b_q, b_k, b_v, Qb, Kfb, Vfb);
    attn_kernel<<<dim3(8, 64), 256, 0, stream>>>(Qb, Kfb, Vfb, M32, out);
  } else {
    // Legacy round-13 path (4 launches): mask overlays dead phase-1 region.
    unsigned int* M32 = (unsigned int*)(ws + 0);               // 32 MB
    prep_kernel<<<19456, 256, 0, stream>>>(x_q, x_kv, xq_bf, xkv_bf,
                                           w_q, w_k, w_v, wqt, wkt, wvt);
    proj_gemm_kernel<<<dim3(8, 64, 3), 256, 0, stream>>>(
        xq_bf, xkv_bf, wqt, wkt, wvt, b_q, b_k, b_v, Qb, Kfb, Vfb);
    maskf_kernel<<<32768, 256, 0, stream>>>(amask, M32);
    attn_kernel<<<dim3(8, 64), 256, 0, stream>>>(Qb, Kfb, Vfb, M32, out);
  }
}